// Round 7
// baseline (376.128 us; speedup 1.0000x reference)
//
#include <hip/hip_runtime.h>

// GraphSAGE 3-layer, N=50000 nodes, D=128, E=640000 edges, fp32 in/out.
// R1: unroll 1 + launch_bounds (spill fix).  R2: 8 gathers in flight.
// R3: bf16 MFMA + XOR-swizzled LDS.          R4: bf16 gather (256B/row).
// R5: neighbor-phase-first GEMM (residual from LDS), bf16-only intermediates.
// R6: bucket scatter was writeback-bound (35MB for 1.28MB payload) -> compact
//     CSR (hist + wave-scan range alloc + packed scatter, ~13 entries/line).
//     aggregate fused INTO the GEMM: per-64-row block gathers its neighbor
//     means straight into a 2nd LDS tile (wave=16 nodes, prefetch 1 ahead),
//     one __syncthreads, then dual MFMA. Kills 3 dispatches + 25.6MB/layer.

#define DFEAT 128

typedef unsigned short ushort_t;
typedef unsigned int uint_t;
using short8  = __attribute__((ext_vector_type(8))) short;
using floatx4 = __attribute__((ext_vector_type(4))) float;

static __device__ __forceinline__ ushort_t f2bf(float f) {
    unsigned int u = __float_as_uint(f);
    u = (u + 0x7fffu + ((u >> 16) & 1u)) >> 16;   // RNE
    return (ushort_t)u;
}
static __device__ __forceinline__ float bflo(uint_t v) { return __uint_as_float(v << 16); }
static __device__ __forceinline__ float bfhi(uint_t v) { return __uint_as_float(v & 0xffff0000u); }
static __device__ __forceinline__ float bf2f(ushort_t u) { return __uint_as_float((uint_t)u << 16); }

// fused prep: [0,zb) zero cnt(+gcur) ; [zb,zb+384) W -> bf16 [n][k] ;
// [zb+384,...) fp32->bf16 copy of feat (8 elems/thread).
__global__ __launch_bounds__(256) void prep_all(const float* __restrict__ w0,
                                                const float* __restrict__ w1,
                                                const float* __restrict__ w2,
                                                const float* __restrict__ w3,
                                                const float* __restrict__ w4,
                                                const float* __restrict__ w5,
                                                ushort_t* __restrict__ wt,
                                                const float* __restrict__ feat,
                                                ushort_t* __restrict__ featb,
                                                int* __restrict__ cnt,
                                                int nz, int zb) {
    int b = blockIdx.x;
    if (b < zb) {
        int i = b * 1024 + threadIdx.x * 4;
        if (i < nz) *(int4*)&cnt[i] = make_int4(0, 0, 0, 0);   // nz%4==0
        return;
    }
    b -= zb;
    if (b < 384) {
        const float* ws[6] = {w0, w1, w2, w3, w4, w5};
        const float* W = ws[b >> 6];
        ushort_t* O = wt + (size_t)(b >> 6) * DFEAT * DFEAT;
        int idx = (b & 63) * 256 + threadIdx.x;      // 0..16383
        int k = idx >> 7, nn = idx & 127;
        O[nn * DFEAT + k] = f2bf(W[idx]);            // read coalesced
        return;
    }
    b -= 384;
    int i = b * 256 + threadIdx.x;                   // float8 index
    const float4* p = (const float4*)feat + (size_t)2 * i;
    float4 v0 = p[0], v1 = p[1];
    short8 u;
    u[0] = (short)f2bf(v0.x); u[1] = (short)f2bf(v0.y);
    u[2] = (short)f2bf(v0.z); u[3] = (short)f2bf(v0.w);
    u[4] = (short)f2bf(v1.x); u[5] = (short)f2bf(v1.y);
    u[6] = (short)f2bf(v1.z); u[7] = (short)f2bf(v1.w);
    *(short8*)&featb[(size_t)i * 8] = u;
}

__global__ void hist_k(const int* __restrict__ dst, int* __restrict__ cnt, int E) {
    int i = blockIdx.x * blockDim.x + threadIdx.x;
    if (i < E) atomicAdd(&cnt[dst[i]], 1);
}

// per-node contiguous range alloc: wave shfl-scan + 1 global atomic per wave.
// meta[node] = {start, deg}; cursor[node] = start.
__global__ __launch_bounds__(256) void alloc_ranges(const int* __restrict__ cnt,
                                                    int2* __restrict__ meta,
                                                    int* __restrict__ cursor,
                                                    int* __restrict__ gcur, int n) {
    int node = blockIdx.x * 256 + threadIdx.x;
    int lane = threadIdx.x & 63;
    int deg = (node < n) ? cnt[node] : 0;
    int incl = deg;
#pragma unroll
    for (int d = 1; d < 64; d <<= 1) {
        int v = __shfl_up(incl, d);
        if (lane >= d) incl += v;
    }
    int total = __shfl(incl, 63);
    int base = 0;
    if (lane == 63 && total > 0) base = atomicAdd(gcur, total);
    base = __shfl(base, 63);
    int start = base + incl - deg;
    if (node < n) {
        meta[node] = make_int2(start, deg);
        cursor[node] = start;
    }
}

__global__ void scatter_csr(const int* __restrict__ src, const int* __restrict__ dst,
                            int* __restrict__ cursor, ushort_t* __restrict__ csr, int E) {
    int i = blockIdx.x * blockDim.x + threadIdx.x;
    if (i >= E) return;
    int d = dst[i];
    int pos = atomicAdd(&cursor[d], 1);
    csr[pos] = (ushort_t)src[i];
}

// Fused: per block of 64 rows: stage self tile -> LDS, gather neighbor means
// -> 2nd LDS tile, then out = relu(x@Ws + nb@Wn + b) + x (residual from LDS).
// 256 thr = 4 waves; wave w: gathers nodes [w*16, w*16+16), owns cols
// [32w,32w+32) in the GEMM. mfma_f32_16x16x32_bf16: A row=lane&15,
// k=8*(lane>>4)+j; B col=lane&15 same k; D col=lane&15,row=4*(lane>>4)+reg.
__global__ __launch_bounds__(256) void sage_fused(const ushort_t* __restrict__ xb,
                                                  const int2* __restrict__ meta,
                                                  const ushort_t* __restrict__ csr,
                                                  const ushort_t* __restrict__ WsT,
                                                  const ushort_t* __restrict__ WnT,
                                                  const float* __restrict__ bias,
                                                  float* __restrict__ outf,
                                                  ushort_t* __restrict__ outb, int n) {
    __shared__ ushort_t As[64 * DFEAT];   // self tile (also residual source)
    __shared__ ushort_t Nb[64 * DFEAT];   // neighbor-mean tile
    int t = threadIdx.x;
    int lane = t & 63;
    int w = t >> 6;            // wave 0..3
    int lr = lane & 15;
    int lg = lane >> 4;        // 0..3
    int row0 = blockIdx.x * 64;

    // 1) stage self tile, swizzled: chunk c -> c^(r&7)
#pragma unroll
    for (int i = 0; i < 4; ++i) {
        int slot = i * 256 + t;
        int r = slot >> 4;            // row 0..63
        int c = slot & 15;            // 16B chunk
        int gr = row0 + r;
        short8 u = (short8)0;
        if (gr < n) u = *(const short8*)&xb[(size_t)gr * DFEAT + c * 8];
        *(short8*)&As[r * DFEAT + (c ^ (r & 7)) * 8] = u;
    }

    // 2) gather/mean: wave w -> tile rows [w*16, w*16+16)
    const uint_t* x1 = (const uint_t*)xb;    // row stride 64 uints
    int nbase = row0 + w * 16;
    // software pipeline: meta + lane-index one node ahead
    int cn_n = 0, bs_n = 0, ix_n = 0;
    if (nbase < n) {
        int2 md = meta[nbase];
        cn_n = md.y; bs_n = md.x;
        int mm = cn_n < 64 ? cn_n : 64;
        ix_n = (lane < mm) ? (int)csr[bs_n + lane] : 0;
    }
#pragma unroll 1
    for (int i = 0; i < 16; ++i) {
        int node = nbase + i;
        int cn = cn_n, base = bs_n, myidx = ix_n;
        if (i < 15) {
            int nd = node + 1;
            cn_n = 0; bs_n = 0; ix_n = 0;
            if (nd < n) {
                int2 md = meta[nd];
                cn_n = md.y; bs_n = md.x;
                int mm = cn_n < 64 ? cn_n : 64;
                ix_n = (lane < mm) ? (int)csr[bs_n + lane] : 0;
            }
        }
        float tx = 0.f, ty = 0.f;
        if (node < n && cn > 0) {
            int m = cn < 64 ? cn : 64;
            float sx[8], sy[8];
#pragma unroll
            for (int j = 0; j < 8; ++j) { sx[j] = 0.f; sy[j] = 0.f; }
#pragma unroll 1
            for (int ii = 0; ii < m; ii += 8) {
                int s[8];
#pragma unroll
                for (int j = 0; j < 8; ++j) s[j] = __shfl(myidx, ii + j);
#pragma unroll
                for (int j = 1; j < 8; ++j) s[j] = (ii + j < m) ? s[j] : s[0];
                uint_t v[8];
#pragma unroll
                for (int j = 0; j < 8; ++j) v[j] = x1[(size_t)s[j] * 64 + lane];
                sx[0] += bflo(v[0]); sy[0] += bfhi(v[0]);
#pragma unroll
                for (int j = 1; j < 8; ++j) {
                    if (ii + j < m) { sx[j] += bflo(v[j]); sy[j] += bfhi(v[j]); }
                }
            }
            tx = ((sx[0] + sx[1]) + (sx[2] + sx[3])) + ((sx[4] + sx[5]) + (sx[6] + sx[7]));
            ty = ((sy[0] + sy[1]) + (sy[2] + sy[3])) + ((sy[4] + sy[5]) + (sy[6] + sy[7]));
            // rare tail (deg > 64): serial, uniform index loads
            for (int ii = 64; ii < cn; ++ii) {
                uint_t v = x1[(size_t)csr[base + ii] * 64 + lane];
                tx += bflo(v); ty += bfhi(v);
            }
            float inv = 1.0f / (float)cn;
            tx *= inv; ty *= inv;
        }
        // write lane's 2 cols (one uint) into Nb row r, swizzled
        int r = w * 16 + i;
        int c = lane >> 2;               // chunk 0..15
        int e = (2 * lane) & 7;          // even element within chunk
        uint_t o = ((uint_t)f2bf(ty) << 16) | (uint_t)f2bf(tx);
        *(uint_t*)&Nb[r * DFEAT + (c ^ (r & 7)) * 8 + e] = o;
    }
    __syncthreads();

    // 3) dual GEMM from LDS (neighbor tile + self tile)
    floatx4 acc[4][2];
#pragma unroll
    for (int m = 0; m < 4; ++m)
#pragma unroll
        for (int tt = 0; tt < 2; ++tt) acc[m][tt] = (floatx4)0.f;

#pragma unroll
    for (int s = 0; s < 4; ++s) {
        short8 a[4], b[2];
        // neighbor phase
#pragma unroll
        for (int m = 0; m < 4; ++m) {
            int r = m * 16 + lr;
            int c = s * 4 + lg;
            a[m] = *(const short8*)&Nb[r * DFEAT + (c ^ (r & 7)) * 8];
        }
#pragma unroll
        for (int tt = 0; tt < 2; ++tt) {
            int nn = w * 32 + tt * 16 + lr;
            b[tt] = *(const short8*)&WnT[(size_t)nn * DFEAT + s * 32 + lg * 8];
        }
#pragma unroll
        for (int m = 0; m < 4; ++m)
#pragma unroll
            for (int tt = 0; tt < 2; ++tt)
                acc[m][tt] = __builtin_amdgcn_mfma_f32_16x16x32_bf16(a[m], b[tt], acc[m][tt], 0, 0, 0);
        // self phase
#pragma unroll
        for (int m = 0; m < 4; ++m) {
            int r = m * 16 + lr;
            int c = s * 4 + lg;
            a[m] = *(const short8*)&As[r * DFEAT + (c ^ (r & 7)) * 8];
        }
#pragma unroll
        for (int tt = 0; tt < 2; ++tt) {
            int nn = w * 32 + tt * 16 + lr;
            b[tt] = *(const short8*)&WsT[(size_t)nn * DFEAT + s * 32 + lg * 8];
        }
#pragma unroll
        for (int m = 0; m < 4; ++m)
#pragma unroll
            for (int tt = 0; tt < 2; ++tt)
                acc[m][tt] = __builtin_amdgcn_mfma_f32_16x16x32_bf16(a[m], b[tt], acc[m][tt], 0, 0, 0);
    }

    // 4) epilogue: bias + relu + residual-from-LDS (As == self tile)
#pragma unroll
    for (int tt = 0; tt < 2; ++tt) {
        int col = w * 32 + tt * 16 + lr;
        float bb = bias[col];
        int cch = col >> 3, cel = col & 7;
#pragma unroll
        for (int m = 0; m < 4; ++m) {
#pragma unroll
            for (int j = 0; j < 4; ++j) {
                int r = m * 16 + lg * 4 + j;
                int gr = row0 + r;
                if (gr < n) {
                    float xr = bf2f(As[r * DFEAT + (cch ^ (r & 7)) * 8 + cel]);
                    float v = fmaxf(acc[m][tt][j] + bb, 0.f) + xr;
                    if (outf) outf[(size_t)gr * DFEAT + col] = v;
                    if (outb) outb[(size_t)gr * DFEAT + col] = f2bf(v);
                }
            }
        }
    }
}

extern "C" void kernel_launch(void* const* d_in, const int* in_sizes, int n_in,
                              void* d_out, int out_size, void* d_ws, size_t ws_size,
                              hipStream_t stream) {
    const float* feat = (const float*)d_in[0];
    const int*   src  = (const int*)d_in[1];
    const int*   dst  = (const int*)d_in[2];
    // d_in[3] = etype (unused by reference math)
    const float* Ws1 = (const float*)d_in[4];
    const float* Wn1 = (const float*)d_in[5];
    const float* b1  = (const float*)d_in[6];
    const float* Ws2 = (const float*)d_in[7];
    const float* Wn2 = (const float*)d_in[8];
    const float* b2  = (const float*)d_in[9];
    const float* Ws3 = (const float*)d_in[10];
    const float* Wn3 = (const float*)d_in[11];
    const float* b3  = (const float*)d_in[12];

    int n = in_sizes[0] / DFEAT;   // 50000
    int E = in_sizes[1];           // 640000

    // workspace layout (256B aligned)
    char* ws = (char*)d_ws;
    size_t off = 0;
    auto alloc = [&](size_t bytes) {
        size_t o = off;
        off = (off + bytes + 255) & ~(size_t)255;
        return o;
    };
    int nz = n + 64;                // cnt + gcur tail, multiple of 4
    int*      cnt    = (int*)(ws + alloc((size_t)nz * sizeof(int)));
    int2*     meta   = (int2*)(ws + alloc((size_t)n * sizeof(int2)));
    int*      cursor = (int*)(ws + alloc((size_t)n * sizeof(int)));
    ushort_t* csr    = (ushort_t*)(ws + alloc((size_t)E * sizeof(ushort_t)));
    ushort_t* featb  = (ushort_t*)(ws + alloc((size_t)n * DFEAT * sizeof(ushort_t)));
    ushort_t* h1b    = (ushort_t*)(ws + alloc((size_t)n * DFEAT * sizeof(ushort_t)));
    ushort_t* Wt     = (ushort_t*)(ws + alloc((size_t)6 * DFEAT * DFEAT * sizeof(ushort_t)));
    ushort_t* h2b    = featb;   // featb dead after layer-1
    int*      gcur   = cnt + n;
    (void)ws_size;

    ushort_t* Ws1T = Wt + 0 * DFEAT * DFEAT;
    ushort_t* Wn1T = Wt + 1 * DFEAT * DFEAT;
    ushort_t* Ws2T = Wt + 2 * DFEAT * DFEAT;
    ushort_t* Wn2T = Wt + 3 * DFEAT * DFEAT;
    ushort_t* Ws3T = Wt + 4 * DFEAT * DFEAT;
    ushort_t* Wn3T = Wt + 5 * DFEAT * DFEAT;

    float* outp = (float*)d_out;

    // prep: zero cnt/gcur + transpose weights + feat->bf16
    int zb = (nz + 1023) / 1024;
    int cv = (n * DFEAT / 8 + 255) / 256;
    prep_all<<<zb + 384 + cv, 256, 0, stream>>>(Ws1, Wn1, Ws2, Wn2, Ws3, Wn3, Wt,
                                                feat, featb, cnt, nz, zb);
    // CSR build
    hist_k<<<(E + 255) / 256, 256, 0, stream>>>(dst, cnt, E);
    alloc_ranges<<<(n + 255) / 256, 256, 0, stream>>>(cnt, meta, cursor, gcur, n);
    scatter_csr<<<(E + 255) / 256, 256, 0, stream>>>(src, dst, cursor, csr, E);

    int gemm_blocks = (n + 63) / 64;
    // layer 1: featb -> h1b
    sage_fused<<<gemm_blocks, 256, 0, stream>>>(featb, meta, csr, Ws1T, Wn1T, b1,
                                                nullptr, h1b, n);
    // layer 2: h1b -> h2b (aliases featb; disjoint from h1b)
    sage_fused<<<gemm_blocks, 256, 0, stream>>>(h1b, meta, csr, Ws2T, Wn2T, b2,
                                                nullptr, h2b, n);
    // layer 3: h2b -> d_out (fp32)
    sage_fused<<<gemm_blocks, 256, 0, stream>>>(h2b, meta, csr, Ws3T, Wn3T, b3,
                                                outp, nullptr, n);
}

// Round 8
// 212.484 us; speedup vs baseline: 1.7702x; 1.7702x over previous
//
#include <hip/hip_runtime.h>

// GraphSAGE 3-layer, N=50000 nodes, D=128, E=640000 edges, fp32 in/out.
// R1: unroll 1 + launch_bounds (spill fix).  R2: deep gather pipelining.
// R3: bf16 MFMA + XOR-swizzled LDS.          R4: bf16 gather.
// R5: neighbor-first GEMM (residual from LDS), bf16-only intermediates.
// R6: compact-CSR build (hist/scan-alloc/scatter) fixed bucket writeback.
// R7: FAILED fusion of aggregate into GEMM (gather lost TLP: 782 blocks vs
//     12500; 100us vs 37us). Reverted.
// R8: column-PANEL activation layout [4][n][32cols]: each 3.2MB panel fits
//     one XCD 4MiB L2; aggregate block p=bid&3 -> panel p pinned to XCDs
//     {p,p+4} via round-robin dispatch -> gathers become L2 hits.
//     8-lane group per node, uint2/lane, 8 gathers in flight, exact degrees.

#define DFEAT 128

typedef unsigned short ushort_t;
typedef unsigned int uint_t;
using short8  = __attribute__((ext_vector_type(8))) short;
using floatx4 = __attribute__((ext_vector_type(4))) float;

static __device__ __forceinline__ ushort_t f2bf(float f) {
    unsigned int u = __float_as_uint(f);
    u = (u + 0x7fffu + ((u >> 16) & 1u)) >> 16;   // RNE
    return (ushort_t)u;
}
static __device__ __forceinline__ float bflo(uint_t v) { return __uint_as_float(v << 16); }
static __device__ __forceinline__ float bfhi(uint_t v) { return __uint_as_float(v & 0xffff0000u); }
static __device__ __forceinline__ float bf2f(ushort_t u) { return __uint_as_float((uint_t)u << 16); }

// fused prep: [0,zb) zero cnt+gcur ; [zb,zb+384) W -> bf16 [n][k] ;
// [zb+384,...) fp32 feat -> bf16 PANELS (8 cols/thread).
__global__ __launch_bounds__(256) void prep_all(const float* __restrict__ w0,
                                                const float* __restrict__ w1,
                                                const float* __restrict__ w2,
                                                const float* __restrict__ w3,
                                                const float* __restrict__ w4,
                                                const float* __restrict__ w5,
                                                ushort_t* __restrict__ wt,
                                                const float* __restrict__ feat,
                                                ushort_t* __restrict__ featb,
                                                int* __restrict__ cnt,
                                                int n, int nz, int zb) {
    int b = blockIdx.x;
    if (b < zb) {
        int i = b * 1024 + threadIdx.x * 4;
        if (i < nz) *(int4*)&cnt[i] = make_int4(0, 0, 0, 0);   // nz%4==0
        return;
    }
    b -= zb;
    if (b < 384) {
        const float* ws[6] = {w0, w1, w2, w3, w4, w5};
        const float* W = ws[b >> 6];
        ushort_t* O = wt + (size_t)(b >> 6) * DFEAT * DFEAT;
        int idx = (b & 63) * 256 + threadIdx.x;      // 0..16383
        int k = idx >> 7, nn = idx & 127;
        O[nn * DFEAT + k] = f2bf(W[idx]);            // read coalesced
        return;
    }
    b -= 384;
    int i = b * 256 + threadIdx.x;                   // float8-chunk index, n*16 total
    int node = i >> 4, c = i & 15;                   // chunk c = cols [8c, 8c+8)
    const float4* p = (const float4*)feat + (size_t)2 * i;
    float4 v0 = p[0], v1 = p[1];
    short8 u;
    u[0] = (short)f2bf(v0.x); u[1] = (short)f2bf(v0.y);
    u[2] = (short)f2bf(v0.z); u[3] = (short)f2bf(v0.w);
    u[4] = (short)f2bf(v1.x); u[5] = (short)f2bf(v1.y);
    u[6] = (short)f2bf(v1.z); u[7] = (short)f2bf(v1.w);
    *(short8*)&featb[(size_t)(c >> 2) * n * 32 + (size_t)node * 32 + (c & 3) * 8] = u;
}

__global__ void hist_k(const int* __restrict__ dst, int* __restrict__ cnt, int E) {
    int i = blockIdx.x * blockDim.x + threadIdx.x;
    if (i < E) atomicAdd(&cnt[dst[i]], 1);
}

// per-node contiguous range alloc: wave shfl-scan + 1 global atomic per wave.
__global__ __launch_bounds__(256) void alloc_ranges(const int* __restrict__ cnt,
                                                    int2* __restrict__ meta,
                                                    int* __restrict__ cursor,
                                                    int* __restrict__ gcur, int n) {
    int node = blockIdx.x * 256 + threadIdx.x;
    int lane = threadIdx.x & 63;
    int deg = (node < n) ? cnt[node] : 0;
    int incl = deg;
#pragma unroll
    for (int d = 1; d < 64; d <<= 1) {
        int v = __shfl_up(incl, d);
        if (lane >= d) incl += v;
    }
    int total = __shfl(incl, 63);
    int base = 0;
    if (lane == 63 && total > 0) base = atomicAdd(gcur, total);
    base = __shfl(base, 63);
    int start = base + incl - deg;
    if (node < n) {
        meta[node] = make_int2(start, deg);
        cursor[node] = start;
    }
}

__global__ void scatter_csr(const int* __restrict__ src, const int* __restrict__ dst,
                            int* __restrict__ cursor, ushort_t* __restrict__ csr, int E) {
    int i = blockIdx.x * blockDim.x + threadIdx.x;
    if (i >= E) return;
    int d = dst[i];
    int pos = atomicAdd(&cursor[d], 1);
    csr[pos] = (ushort_t)src[i];
}

// panel aggregate: block handles panel p = bid&3 and 32 nodes (8-lane group
// per node). Each lane owns 4 cols (uint2=8B); 8 gather rounds in flight.
__global__ __launch_bounds__(256) void aggregate_panel(const ushort_t* __restrict__ xpan,
                                                       const int2* __restrict__ meta,
                                                       const ushort_t* __restrict__ csr,
                                                       ushort_t* __restrict__ npan, int n) {
    int p = blockIdx.x & 3;
    int g = threadIdx.x >> 3;            // group 0..31
    int sub = threadIdx.x & 7;
    int node = (blockIdx.x >> 2) * 32 + g;
    if (node >= n) return;
    int2 md = meta[node];
    int base = md.x, cn = md.y;
    const uint2* xp = (const uint2*)(xpan + (size_t)p * n * 32);   // row = 8 uint2
    uint2* np = (uint2*)(npan + (size_t)p * n * 32);

    float a[4][4];
#pragma unroll
    for (int s = 0; s < 4; ++s)
#pragma unroll
        for (int c = 0; c < 4; ++c) a[s][c] = 0.f;

#pragma unroll 1
    for (int r = 0; r < cn; r += 8) {
        int idx = 0;
        if (r + sub < cn) idx = (int)csr[base + r + sub];
        int s[8];
#pragma unroll
        for (int j = 0; j < 8; ++j) s[j] = __shfl(idx, j, 8);
#pragma unroll
        for (int j = 1; j < 8; ++j) s[j] = (r + j < cn) ? s[j] : s[0];
        uint2 v[8];
#pragma unroll
        for (int j = 0; j < 8; ++j) v[j] = xp[(size_t)s[j] * 8 + sub];
        a[0][0] += bflo(v[0].x); a[0][1] += bfhi(v[0].x);
        a[0][2] += bflo(v[0].y); a[0][3] += bfhi(v[0].y);
#pragma unroll
        for (int j = 1; j < 8; ++j) {
            if (r + j < cn) {
                a[j & 3][0] += bflo(v[j].x); a[j & 3][1] += bfhi(v[j].x);
                a[j & 3][2] += bflo(v[j].y); a[j & 3][3] += bfhi(v[j].y);
            }
        }
    }
    float c0 = (a[0][0] + a[1][0]) + (a[2][0] + a[3][0]);
    float c1 = (a[0][1] + a[1][1]) + (a[2][1] + a[3][1]);
    float c2 = (a[0][2] + a[1][2]) + (a[2][2] + a[3][2]);
    float c3 = (a[0][3] + a[1][3]) + (a[2][3] + a[3][3]);
    float inv = cn > 0 ? 1.0f / (float)cn : 0.0f;
    uint2 o;
    o.x = ((uint_t)f2bf(c1 * inv) << 16) | (uint_t)f2bf(c0 * inv);
    o.y = ((uint_t)f2bf(c3 * inv) << 16) | (uint_t)f2bf(c2 * inv);
    np[(size_t)node * 8 + sub] = o;
}

// out = relu(x@Ws + nb@Wn + b) + x. A-operands read from PANELS; outb written
// to PANELS (wave w's cols [32w,32w+32) == panel w). Neighbor phase FIRST,
// self LAST -> residual from LDS. mfma_f32_16x16x32_bf16 layout m89-verified.
__global__ __launch_bounds__(256) void sage_gemm_mfma(const ushort_t* __restrict__ xpan,
                                                      const ushort_t* __restrict__ nbpan,
                                                      const ushort_t* __restrict__ WsT,
                                                      const ushort_t* __restrict__ WnT,
                                                      const float* __restrict__ bias,
                                                      float* __restrict__ outf,
                                                      ushort_t* __restrict__ outbpan, int n) {
    __shared__ ushort_t As[64 * DFEAT];   // 16 KB, XOR-swizzled 16B chunks
    int t = threadIdx.x;
    int lane = t & 63;
    int w = t >> 6;            // wave 0..3
    int lr = lane & 15;
    int lg = lane >> 4;        // 0..3
    int row0 = blockIdx.x * 64;

    floatx4 acc[4][2];
#pragma unroll
    for (int m = 0; m < 4; ++m)
#pragma unroll
        for (int tt = 0; tt < 2; ++tt) acc[m][tt] = (floatx4)0.f;

#pragma unroll 1
    for (int phase = 0; phase < 2; ++phase) {
        const ushort_t* A = phase ? xpan : nbpan;    // self LAST
        const ushort_t* W = phase ? WsT : WnT;
        __syncthreads();   // protect As against previous phase's readers
        // stage 64 rows x 128 bf16 cols from panels, swizzle chunk c -> c^(r&7)
#pragma unroll
        for (int i = 0; i < 4; ++i) {
            int slot = i * 256 + t;
            int r = slot >> 4;            // row 0..63
            int c = slot & 15;            // 16B chunk
            int gr = row0 + r;
            short8 u = (short8)0;
            if (gr < n)
                u = *(const short8*)&A[(size_t)(c >> 2) * n * 32 + (size_t)gr * 32 + (c & 3) * 8];
            *(short8*)&As[r * DFEAT + (c ^ (r & 7)) * 8] = u;
        }
        __syncthreads();
#pragma unroll
        for (int s = 0; s < 4; ++s) {
            short8 a[4], b[2];
#pragma unroll
            for (int m = 0; m < 4; ++m) {
                int r = m * 16 + lr;
                int c = s * 4 + lg;
                a[m] = *(const short8*)&As[r * DFEAT + (c ^ (r & 7)) * 8];
            }
#pragma unroll
            for (int tt = 0; tt < 2; ++tt) {
                int nn = w * 32 + tt * 16 + lr;
                b[tt] = *(const short8*)&W[(size_t)nn * DFEAT + s * 32 + lg * 8];
            }
#pragma unroll
            for (int m = 0; m < 4; ++m)
#pragma unroll
                for (int tt = 0; tt < 2; ++tt)
                    acc[m][tt] = __builtin_amdgcn_mfma_f32_16x16x32_bf16(
                        a[m], b[tt], acc[m][tt], 0, 0, 0);
        }
    }
    // epilogue: bias + relu + residual-from-LDS (As == self tile)
#pragma unroll
    for (int tt = 0; tt < 2; ++tt) {
        int col = w * 32 + tt * 16 + lr;
        float bb = bias[col];
        int cch = col >> 3, cel = col & 7;
#pragma unroll
        for (int m = 0; m < 4; ++m) {
#pragma unroll
            for (int j = 0; j < 4; ++j) {
                int r = m * 16 + lg * 4 + j;
                int gr = row0 + r;
                if (gr < n) {
                    float xr = bf2f(As[r * DFEAT + (cch ^ (r & 7)) * 8 + cel]);
                    float v = fmaxf(acc[m][tt][j] + bb, 0.f) + xr;
                    if (outf) outf[(size_t)gr * DFEAT + col] = v;
                    if (outbpan)
                        outbpan[(size_t)w * n * 32 + (size_t)gr * 32 + tt * 16 + lr] = f2bf(v);
                }
            }
        }
    }
}

extern "C" void kernel_launch(void* const* d_in, const int* in_sizes, int n_in,
                              void* d_out, int out_size, void* d_ws, size_t ws_size,
                              hipStream_t stream) {
    const float* feat = (const float*)d_in[0];
    const int*   src  = (const int*)d_in[1];
    const int*   dst  = (const int*)d_in[2];
    // d_in[3] = etype (unused by reference math)
    const float* Ws1 = (const float*)d_in[4];
    const float* Wn1 = (const float*)d_in[5];
    const float* b1  = (const float*)d_in[6];
    const float* Ws2 = (const float*)d_in[7];
    const float* Wn2 = (const float*)d_in[8];
    const float* b2  = (const float*)d_in[9];
    const float* Ws3 = (const float*)d_in[10];
    const float* Wn3 = (const float*)d_in[11];
    const float* b3  = (const float*)d_in[12];

    int n = in_sizes[0] / DFEAT;   // 50000
    int E = in_sizes[1];           // 640000

    // workspace layout (256B aligned)
    char* ws = (char*)d_ws;
    size_t off = 0;
    auto alloc = [&](size_t bytes) {
        size_t o = off;
        off = (off + bytes + 255) & ~(size_t)255;
        return o;
    };
    int nz = n + 64;                // cnt + gcur tail, multiple of 4
    int*      cnt    = (int*)(ws + alloc((size_t)nz * sizeof(int)));
    int2*     meta   = (int2*)(ws + alloc((size_t)n * sizeof(int2)));
    int*      cursor = (int*)(ws + alloc((size_t)n * sizeof(int)));
    ushort_t* csr    = (ushort_t*)(ws + alloc((size_t)E * sizeof(ushort_t)));
    ushort_t* featb  = (ushort_t*)(ws + alloc((size_t)n * DFEAT * sizeof(ushort_t)));
    ushort_t* h1b    = (ushort_t*)(ws + alloc((size_t)n * DFEAT * sizeof(ushort_t)));
    ushort_t* npan   = (ushort_t*)(ws + alloc((size_t)n * DFEAT * sizeof(ushort_t)));
    ushort_t* Wt     = (ushort_t*)(ws + alloc((size_t)6 * DFEAT * DFEAT * sizeof(ushort_t)));
    ushort_t* h2b    = featb;   // featb dead after layer-1
    int*      gcur   = cnt + n;
    (void)ws_size;

    ushort_t* Ws1T = Wt + 0 * DFEAT * DFEAT;
    ushort_t* Wn1T = Wt + 1 * DFEAT * DFEAT;
    ushort_t* Ws2T = Wt + 2 * DFEAT * DFEAT;
    ushort_t* Wn2T = Wt + 3 * DFEAT * DFEAT;
    ushort_t* Ws3T = Wt + 4 * DFEAT * DFEAT;
    ushort_t* Wn3T = Wt + 5 * DFEAT * DFEAT;

    float* outp = (float*)d_out;

    // prep: zero cnt/gcur + transpose weights + feat->bf16 panels
    int zb = (nz + 1023) / 1024;
    int cv = (n * DFEAT / 8 + 255) / 256;
    prep_all<<<zb + 384 + cv, 256, 0, stream>>>(Ws1, Wn1, Ws2, Wn2, Ws3, Wn3, Wt,
                                                feat, featb, cnt, n, nz, zb);
    // CSR build
    hist_k<<<(E + 255) / 256, 256, 0, stream>>>(dst, cnt, E);
    alloc_ranges<<<(n + 255) / 256, 256, 0, stream>>>(cnt, meta, cursor, gcur, n);
    scatter_csr<<<(E + 255) / 256, 256, 0, stream>>>(src, dst, cursor, csr, E);

    int agg_blocks  = 4 * ((n + 31) / 32);   // panel = bid&3
    int gemm_blocks = (n + 63) / 64;

    // layer 1: featb -> h1b
    aggregate_panel<<<agg_blocks, 256, 0, stream>>>(featb, meta, csr, npan, n);
    sage_gemm_mfma<<<gemm_blocks, 256, 0, stream>>>(featb, npan, Ws1T, Wn1T, b1,
                                                    nullptr, h1b, n);
    // layer 2: h1b -> h2b (aliases featb)
    aggregate_panel<<<agg_blocks, 256, 0, stream>>>(h1b, meta, csr, npan, n);
    sage_gemm_mfma<<<gemm_blocks, 256, 0, stream>>>(h1b, npan, Ws2T, Wn2T, b2,
                                                    nullptr, h2b, n);
    // layer 3: h2b -> d_out (fp32)
    aggregate_panel<<<agg_blocks, 256, 0, stream>>>(h2b, meta, csr, npan, n);
    sage_gemm_mfma<<<gemm_blocks, 256, 0, stream>>>(h2b, npan, Ws3T, Wn3T, b3,
                                                    outp, nullptr, n);
}